// Round 4
// baseline (852.246 us; speedup 1.0000x reference)
//
#include <hip/hip_runtime.h>
#include <hip/hip_fp16.h>

typedef float    f32x4 __attribute__((ext_vector_type(4)));
typedef _Float16 f16x2 __attribute__((ext_vector_type(2)));
typedef _Float16 f16x4 __attribute__((ext_vector_type(4)));
typedef _Float16 f16x8 __attribute__((ext_vector_type(8)));

#define BS 8
#define NN 2048
#define DK 128
#define DM 64
// log2(e) / sqrt(128): folds softmax temperature AND exp->exp2 conversion into Q
#define QSCALE 0.12751744116926208f

#define MFMA32(a, b, c) __builtin_amdgcn_mfma_f32_16x16x32_f16((a), (b), (c), 0, 0, 0)
#define EXP2(x) __builtin_amdgcn_exp2f(x)

__device__ __forceinline__ f16x2 pkrtz(float x, float y) {
  return __builtin_bit_cast(f16x2, __builtin_amdgcn_cvt_pkrtz(x, y));
}

// ---- fused prep: K f32->f16 (blk<2048), V transpose (blk<4096), q-mean partials ----
__global__ void prep_k(const float* __restrict__ kt, _Float16* __restrict__ kh,
                       const float* __restrict__ vt, _Float16* __restrict__ vT,
                       const float* __restrict__ qt, float* __restrict__ partial) {
  __shared__ float tile[32][33];
  __shared__ float red[256];
  int blk = blockIdx.x;
  int t = threadIdx.x;
  if (blk < 2048) {
    size_t i = ((size_t)blk * 256 + t) * 4;
    f32x4 v = *(const f32x4*)(kt + i);
    f16x4 h;
    h[0] = (_Float16)v[0]; h[1] = (_Float16)v[1];
    h[2] = (_Float16)v[2]; h[3] = (_Float16)v[3];
    *(f16x4*)(kh + i) = h;
  } else if (blk < 4096) {
    blk -= 2048;
    int b = blk >> 8;
    int j0 = (blk & 63) * 32, c0 = ((blk >> 6) & 3) * 32;
    int tx = t & 31, ty = t >> 5;
    const float* src = vt + ((size_t)b * NN + j0) * DK + c0;
#pragma unroll
    for (int i = 0; i < 4; ++i)
      tile[ty + 8 * i][tx] = src[(size_t)(ty + 8 * i) * DK + tx];
    __syncthreads();
    _Float16* dst = vT + ((size_t)b * DK + c0) * NN + j0;
#pragma unroll
    for (int i = 0; i < 4; ++i)
      dst[(size_t)(ty + 8 * i) * NN + tx] = (_Float16)tile[tx][ty + 8 * i];
  } else {
    // q-mean partial sums: 64 blocks, each reduces 256 rows of one batch
    int i = blk - 4096;
    int b = i >> 3, seg = i & 7;
    int c = t & 127, h = t >> 7;
    const float* p = qt + ((size_t)b * NN + seg * 256 + h * 128) * DK + c;
    float s = 0.f;
#pragma unroll 8
    for (int n = 0; n < 128; ++n) s += p[(size_t)n * DK];
    red[t] = s;
    __syncthreads();
    if (t < 128) partial[(size_t)i * 128 + t] = red[t] + red[t + 128];
  }
}

// ---- prior: reduce partials -> bar, then softmax(kernel @ bar^T, axis=batch) ----
__global__ void prior_k(const float* __restrict__ kern, const float* __restrict__ partial,
                        float* __restrict__ prior) {
  __shared__ float barL[8][128];
  __shared__ float lg[16], ex[16];
  int t = threadIdx.x;  // 256
  for (int e = t; e < 1024; e += 256) {
    int b = e >> 7, c = e & 127;
    float s = 0.f;
#pragma unroll
    for (int seg = 0; seg < 8; ++seg) s += partial[(size_t)(b * 8 + seg) * 128 + c];
    barL[b][c] = s * (1.0f / 2048.0f);
  }
  __syncthreads();
  if (t < 16) {
    int m = t >> 3, b = t & 7;
    float s = 0.f;
    for (int c = 0; c < DK; ++c) s += kern[m * DK + c] * barL[b][c];
    lg[t] = s;
  }
  __syncthreads();
  if (t < 16) {
    int m = t >> 3;
    float mx = lg[m * 8];
    for (int i = 1; i < 8; ++i) mx = fmaxf(mx, lg[m * 8 + i]);
    ex[t] = __expf(lg[t] - mx);
  }
  __syncthreads();
  if (t < 16) {
    int m = t >> 3;
    float sm = 0.f;
    for (int i = 0; i < 8; ++i) sm += ex[m * 8 + i];
    prior[t] = ex[t] / sm;  // flat[m*8+b]; attn reads flat[b*2+m] (TF reshape quirk)
  }
}

// ---------------- main: mixture flash attention ----------------
// grid 512 x 512thr: b = blk&7, qb = blk>>3 (32 queries). 8 waves = 8-way key split
// (256 keys each, 8 iters of 32). Register double-buffer (ka/va <-> kb/vb) keeps a
// full iteration's 16 loads in flight -> MLP ~16 (was ~2: compiler recycled temps).
// K rows permuted so two 16x16x32 S^T D-frags concatenate into the x32 B-operand
// for PV; V^T gives contiguous f16x8 A-frags. l via ones-MFMA; exp2 w/ folded scale.
__global__ __launch_bounds__(512, 4) void attn_k(const float* __restrict__ qt,
                                                 const _Float16* __restrict__ kh,
                                                 const _Float16* __restrict__ vT,
                                                 const float* __restrict__ prior,
                                                 float* __restrict__ out) {
  const int b = blockIdx.x & 7;
  const int qb = blockIdx.x >> 3;
  const int wv = threadIdx.x >> 6;  // 0..7
  const int lane = threadIdx.x & 63;
  const int quad = lane >> 4, l16 = lane & 15;
  const int perm = ((l16 >> 2) << 3) | (l16 & 3);
  const size_t bq = (size_t)b * (NN * DK);

  // Q fragments: f32 load + scale + pack to f16 in-register
  f16x8 qf[2][2][2];  // [mix][qtile][chunk]
#pragma unroll
  for (int m = 0; m < 2; ++m)
#pragma unroll
    for (int u = 0; u < 2; ++u)
#pragma unroll
      for (int c = 0; c < 2; ++c) {
        const float* qp = qt + bq + (size_t)m * (1024 * DK) +
                          (size_t)(qb * 32 + u * 16 + l16) * DM + quad * 8 + c * 32;
        f32x4 v0 = *(const f32x4*)qp;
        f32x4 v1 = *(const f32x4*)(qp + 4);
        union { f16x8 v; f16x2 h[4]; } w;
        w.h[0] = pkrtz(v0[0] * QSCALE, v0[1] * QSCALE);
        w.h[1] = pkrtz(v0[2] * QSCALE, v0[3] * QSCALE);
        w.h[2] = pkrtz(v1[0] * QSCALE, v1[1] * QSCALE);
        w.h[3] = pkrtz(v1[2] * QSCALE, v1[3] * QSCALE);
        qf[m][u][c] = w.v;
      }

  const _Float16* kp0 = kh + bq + (size_t)(wv * 256 + perm) * DM + quad * 8;
  const _Float16* vp0 = vT + (size_t)b * (DK * NN) + (size_t)l16 * NN + wv * 256 + quad * 8;

  const f32x4 z = {0.f, 0.f, 0.f, 0.f};
  f32x4 acc[2][2][8];
  f32x4 lacc[2][2];
#pragma unroll
  for (int m = 0; m < 2; ++m)
#pragma unroll
    for (int u = 0; u < 2; ++u) {
      lacc[m][u] = z;
#pragma unroll
      for (int cc = 0; cc < 8; ++cc) acc[m][u][cc] = z;
    }
  const _Float16 one = (_Float16)1.0f;
  const f16x8 ones = {one, one, one, one, one, one, one, one};

  f16x8 ka[8], va[8], kb[8], vb[8];

  auto ldK = [&](f16x8* d, const _Float16* p) {
#pragma unroll
    for (int tt = 0; tt < 2; ++tt) {
      d[tt * 4 + 0] = *(const f16x8*)(p + tt * 256);
      d[tt * 4 + 1] = *(const f16x8*)(p + tt * 256 + 32);
      d[tt * 4 + 2] = *(const f16x8*)(p + tt * 256 + 1024 * DK);
      d[tt * 4 + 3] = *(const f16x8*)(p + tt * 256 + 1024 * DK + 32);
    }
  };
  auto ldV = [&](f16x8* d, const _Float16* p) {
#pragma unroll
    for (int cc = 0; cc < 8; ++cc) d[cc] = *(const f16x8*)(p + (size_t)cc * (16 * NN));
  };
  auto compute = [&](const f16x8* kf, const f16x8* vf) {
    f32x4 s[2][2][2];  // [mix][qtile][subtile]
#pragma unroll
    for (int tt = 0; tt < 2; ++tt)
#pragma unroll
      for (int u = 0; u < 2; ++u) {
        s[0][u][tt] = MFMA32(kf[tt * 4 + 1], qf[0][u][1], MFMA32(kf[tt * 4 + 0], qf[0][u][0], z));
        s[1][u][tt] = MFMA32(kf[tt * 4 + 3], qf[1][u][1], MFMA32(kf[tt * 4 + 2], qf[1][u][0], z));
      }
    f16x8 pb[2][2];
#pragma unroll
    for (int m = 0; m < 2; ++m)
#pragma unroll
      for (int u = 0; u < 2; ++u) {
        union { f16x8 v; f16x2 h[4]; } w;
        w.h[0] = pkrtz(EXP2(s[m][u][0][0]), EXP2(s[m][u][0][1]));
        w.h[1] = pkrtz(EXP2(s[m][u][0][2]), EXP2(s[m][u][0][3]));
        w.h[2] = pkrtz(EXP2(s[m][u][1][0]), EXP2(s[m][u][1][1]));
        w.h[3] = pkrtz(EXP2(s[m][u][1][2]), EXP2(s[m][u][1][3]));
        pb[m][u] = w.v;
        lacc[m][u] = MFMA32(ones, pb[m][u], lacc[m][u]);
      }
#pragma unroll
    for (int cc = 0; cc < 8; ++cc)
#pragma unroll
      for (int m = 0; m < 2; ++m)
#pragma unroll
        for (int u = 0; u < 2; ++u)
          acc[m][u][cc] = MFMA32(vf[cc], pb[m][u], acc[m][u][cc]);
  };

  ldK(ka, kp0);
  ldV(va, vp0);
#pragma unroll
  for (int it = 0; it < 8; it += 2) {
    ldK(kb, kp0 + (size_t)(it + 1) * (32 * DM));
    ldV(vb, vp0 + (it + 1) * 32);
    compute(ka, va);
    const int nx = (it + 2 < 8) ? it + 2 : 0;  // wrap: harmless warm prefetch
    ldK(ka, kp0 + (size_t)nx * (32 * DM));
    ldV(va, vp0 + nx * 32);
    compute(kb, vb);
  }

  // ---- merge 8 key-split waves via LDS atomics, normalize, store ----
  __shared__ float obuf[2][32][130];  // [mix][q][ch]; slot 128 holds l
  for (int i = threadIdx.x; i < 2 * 32 * 130; i += 512) ((float*)obuf)[i] = 0.f;
  __syncthreads();
#pragma unroll
  for (int m = 0; m < 2; ++m)
#pragma unroll
    for (int u = 0; u < 2; ++u) {
#pragma unroll
      for (int cc = 0; cc < 8; ++cc)
#pragma unroll
        for (int r = 0; r < 4; ++r)
          atomicAdd(&obuf[m][u * 16 + l16][cc * 16 + quad * 4 + r], acc[m][u][cc][r]);
      if (quad == 0) atomicAdd(&obuf[m][u * 16 + l16][128], lacc[m][u][0]);
    }
  __syncthreads();
  const float w0 = prior[b * 2 + 0], w1 = prior[b * 2 + 1];
  const int q = threadIdx.x >> 4;           // 0..31
  const int c0 = (threadIdx.x & 15) * 8;    // 0..120
  const float r0 = w0 / obuf[0][q][128];
  const float r1 = w1 / obuf[1][q][128];
  float* op = out + ((size_t)b * NN + qb * 32 + q) * DK + c0;
  f32x4 o0, o1;
#pragma unroll
  for (int e = 0; e < 4; ++e) o0[e] = obuf[0][q][c0 + e] * r0 + obuf[1][q][c0 + e] * r1;
#pragma unroll
  for (int e = 0; e < 4; ++e) o1[e] = obuf[0][q][c0 + 4 + e] * r0 + obuf[1][q][c0 + 4 + e] * r1;
  *(f32x4*)(op) = o0;
  *(f32x4*)(op + 4) = o1;
}

extern "C" void kernel_launch(void* const* d_in, const int* in_sizes, int n_in,
                              void* d_out, int out_size, void* d_ws, size_t ws_size,
                              hipStream_t stream) {
  const float* qt = (const float*)d_in[0];
  const float* kt = (const float*)d_in[1];
  const float* vt = (const float*)d_in[2];
  const float* kern = (const float*)d_in[3];
  float* out = (float*)d_out;

  char* ws = (char*)d_ws;
  float* prior = (float*)ws;                 // 16 floats
  float* partial = (float*)ws + 256;         // 64*128 floats (32 KB)
  _Float16* khp = (_Float16*)(ws + 65536);   // 2M halfs (4 MB)
  _Float16* vTp = khp + (size_t)BS * NN * DK;

  prep_k<<<dim3(4160), dim3(256), 0, stream>>>(kt, khp, vt, vTp, qt, partial);
  prior_k<<<dim3(1), dim3(256), 0, stream>>>(kern, partial, prior);
  attn_k<<<dim3(512), dim3(512), 0, stream>>>(qt, khp, vTp, prior, out);
}

// Round 5
// 203.702 us; speedup vs baseline: 4.1838x; 4.1838x over previous
//
#include <hip/hip_runtime.h>
#include <hip/hip_fp16.h>

typedef float    f32x4 __attribute__((ext_vector_type(4)));
typedef _Float16 f16x2 __attribute__((ext_vector_type(2)));
typedef _Float16 f16x4 __attribute__((ext_vector_type(4)));
typedef _Float16 f16x8 __attribute__((ext_vector_type(8)));

#define BS 8
#define NN 2048
#define DK 128
#define DM 64
#define MIXOFF (1024 * DK)  // halfs between mix-0 and mix-1 rows of one batch
// log2(e) / sqrt(128): folds softmax temperature AND exp->exp2 conversion into Q
#define QSCALE 0.12751744116926208f

#define MFMA32(a, b, c) __builtin_amdgcn_mfma_f32_16x16x32_f16((a), (b), (c), 0, 0, 0)
#define EXP2(x) __builtin_amdgcn_exp2f(x)

__device__ __forceinline__ f16x2 pkrtz(float x, float y) {
  return __builtin_bit_cast(f16x2, __builtin_amdgcn_cvt_pkrtz(x, y));
}

// ---- fused prep: K f32->f16 (blk<2048), V transpose (blk<4096), q-mean partials ----
__global__ void prep_k(const float* __restrict__ kt, _Float16* __restrict__ kh,
                       const float* __restrict__ vt, _Float16* __restrict__ vT,
                       const float* __restrict__ qt, float* __restrict__ partial) {
  __shared__ float tile[32][33];
  __shared__ float red[256];
  int blk = blockIdx.x;
  int t = threadIdx.x;
  if (blk < 2048) {
    size_t i = ((size_t)blk * 256 + t) * 4;
    f32x4 v = *(const f32x4*)(kt + i);
    f16x4 h;
    h[0] = (_Float16)v[0]; h[1] = (_Float16)v[1];
    h[2] = (_Float16)v[2]; h[3] = (_Float16)v[3];
    *(f16x4*)(kh + i) = h;
  } else if (blk < 4096) {
    blk -= 2048;
    int b = blk >> 8;
    int j0 = (blk & 63) * 32, c0 = ((blk >> 6) & 3) * 32;
    int tx = t & 31, ty = t >> 5;
    const float* src = vt + ((size_t)b * NN + j0) * DK + c0;
#pragma unroll
    for (int i = 0; i < 4; ++i)
      tile[ty + 8 * i][tx] = src[(size_t)(ty + 8 * i) * DK + tx];
    __syncthreads();
    _Float16* dst = vT + ((size_t)b * DK + c0) * NN + j0;
#pragma unroll
    for (int i = 0; i < 4; ++i)
      dst[(size_t)(ty + 8 * i) * NN + tx] = (_Float16)tile[tx][ty + 8 * i];
  } else {
    // q-mean partial sums: 64 blocks, each reduces 256 rows of one batch
    int i = blk - 4096;
    int b = i >> 3, seg = i & 7;
    int c = t & 127, h = t >> 7;
    const float* p = qt + ((size_t)b * NN + seg * 256 + h * 128) * DK + c;
    float s = 0.f;
#pragma unroll 8
    for (int n = 0; n < 128; ++n) s += p[(size_t)n * DK];
    red[t] = s;
    __syncthreads();
    if (t < 128) partial[(size_t)i * 128 + t] = red[t] + red[t + 128];
  }
}

// ---- prior: reduce partials -> bar, then softmax(kernel @ bar^T, axis=batch) ----
__global__ void prior_k(const float* __restrict__ kern, const float* __restrict__ partial,
                        float* __restrict__ prior) {
  __shared__ float barL[8][128];
  __shared__ float lg[16], ex[16];
  int t = threadIdx.x;  // 256
  for (int e = t; e < 1024; e += 256) {
    int b = e >> 7, c = e & 127;
    float s = 0.f;
#pragma unroll
    for (int seg = 0; seg < 8; ++seg) s += partial[(size_t)(b * 8 + seg) * 128 + c];
    barL[b][c] = s * (1.0f / 2048.0f);
  }
  __syncthreads();
  if (t < 16) {
    int m = t >> 3, b = t & 7;
    float s = 0.f;
    for (int c = 0; c < DK; ++c) s += kern[m * DK + c] * barL[b][c];
    lg[t] = s;
  }
  __syncthreads();
  if (t < 16) {
    int m = t >> 3;
    float mx = lg[m * 8];
    for (int i = 1; i < 8; ++i) mx = fmaxf(mx, lg[m * 8 + i]);
    ex[t] = __expf(lg[t] - mx);
  }
  __syncthreads();
  if (t < 16) {
    int m = t >> 3;
    float sm = 0.f;
    for (int i = 0; i < 8; ++i) sm += ex[m * 8 + i];
    prior[t] = ex[t] / sm;  // flat[m*8+b]; attn reads flat[b*2+m] (TF reshape quirk)
  }
}

// K fragment loads for one 32-key iteration: dst[tt*4 + m*2 + c]
#define LDK(dst, IT) do {                                                  \
    const _Float16* p_ = kp0 + (size_t)(IT) * (32 * DM);                   \
    dst[0] = *(const f16x8*)(p_);                                          \
    dst[1] = *(const f16x8*)(p_ + 32);                                     \
    dst[2] = *(const f16x8*)(p_ + MIXOFF);                                 \
    dst[3] = *(const f16x8*)(p_ + MIXOFF + 32);                            \
    dst[4] = *(const f16x8*)(p_ + 256);                                    \
    dst[5] = *(const f16x8*)(p_ + 256 + 32);                               \
    dst[6] = *(const f16x8*)(p_ + 256 + MIXOFF);                           \
    dst[7] = *(const f16x8*)(p_ + 256 + MIXOFF + 32);                      \
  } while (0)

#define LDV(dst, IT) do {                                                  \
    const _Float16* p_ = vp0 + (IT) * 32;                                  \
    _Pragma("unroll")                                                      \
    for (int cc = 0; cc < 8; ++cc)                                         \
      dst[cc] = *(const f16x8*)(p_ + (size_t)cc * (16 * NN));              \
  } while (0)

#define COMPUTE(kf, vf) do {                                               \
    f32x4 s[2][2];                                                         \
    s[0][0] = MFMA32(kf[1], qf[0][1], MFMA32(kf[0], qf[0][0], z));         \
    s[1][0] = MFMA32(kf[3], qf[1][1], MFMA32(kf[2], qf[1][0], z));         \
    s[0][1] = MFMA32(kf[5], qf[0][1], MFMA32(kf[4], qf[0][0], z));         \
    s[1][1] = MFMA32(kf[7], qf[1][1], MFMA32(kf[6], qf[1][0], z));         \
    _Pragma("unroll")                                                      \
    for (int m = 0; m < 2; ++m) {                                          \
      union { f16x8 v; f16x2 h[4]; } w_;                                   \
      w_.h[0] = pkrtz(EXP2(s[m][0][0]), EXP2(s[m][0][1]));                 \
      w_.h[1] = pkrtz(EXP2(s[m][0][2]), EXP2(s[m][0][3]));                 \
      w_.h[2] = pkrtz(EXP2(s[m][1][0]), EXP2(s[m][1][1]));                 \
      w_.h[3] = pkrtz(EXP2(s[m][1][2]), EXP2(s[m][1][3]));                 \
      lacc[m] = MFMA32(ones, w_.v, lacc[m]);                               \
      _Pragma("unroll")                                                    \
      for (int cc = 0; cc < 8; ++cc)                                       \
        acc[m][cc] = MFMA32(vf[cc], w_.v, acc[m][cc]);                     \
    }                                                                      \
  } while (0)

// ---------------- main: mixture flash attention ----------------
// grid 256 (1 block/CU, one round): b = blk&7 (pins batch K/V slab to one XCD L2),
// qb = blk>>3. 4 waves SPLIT QUERIES (16 q each, 64/block) and SHARE the key
// stream -> L1/L2 reuse across waves, no cross-wave merge. 64 iters of 32 keys,
// register double-buffer via constant-index macros (R4's lambda-pointer buffers
// were scratch-spilled: 2.2GB fetch / 1.4GB write of pure spill traffic).
// K rows permuted so two 16x16x32 S^T D-frags concatenate into the x32 B-operand
// for PV; V^T gives contiguous f16x8 A-frags. l via ones-MFMA; exp2 folded scale.
__global__ __launch_bounds__(256, 1) void attn_k(const float* __restrict__ qt,
                                                 const _Float16* __restrict__ kh,
                                                 const _Float16* __restrict__ vT,
                                                 const float* __restrict__ prior,
                                                 float* __restrict__ out) {
  const int b = blockIdx.x & 7;
  const int qb = blockIdx.x >> 3;
  const int wv = threadIdx.x >> 6;  // 0..3 -> query sub-tile
  const int lane = threadIdx.x & 63;
  const int quad = lane >> 4, l16 = lane & 15;
  const int perm = ((l16 >> 2) << 3) | (l16 & 3);
  const size_t bq = (size_t)b * (NN * DK);
  const int q0 = qb * 64 + wv * 16;

  // Q fragments: f32 load + scale + pack to f16 in-register
  f16x8 qf[2][2];  // [mix][chunk]
#pragma unroll
  for (int m = 0; m < 2; ++m)
#pragma unroll
    for (int c = 0; c < 2; ++c) {
      const float* qp = qt + bq + (size_t)m * (1024 * DK) +
                        (size_t)(q0 + l16) * DM + quad * 8 + c * 32;
      f32x4 v0 = *(const f32x4*)qp;
      f32x4 v1 = *(const f32x4*)(qp + 4);
      union { f16x8 v; f16x2 h[4]; } w;
      w.h[0] = pkrtz(v0[0] * QSCALE, v0[1] * QSCALE);
      w.h[1] = pkrtz(v0[2] * QSCALE, v0[3] * QSCALE);
      w.h[2] = pkrtz(v1[0] * QSCALE, v1[1] * QSCALE);
      w.h[3] = pkrtz(v1[2] * QSCALE, v1[3] * QSCALE);
      qf[m][c] = w.v;
    }

  const _Float16* kp0 = kh + bq + (size_t)perm * DM + quad * 8;
  const _Float16* vp0 = vT + (size_t)b * (DK * NN) + (size_t)l16 * NN + quad * 8;

  const f32x4 z = {0.f, 0.f, 0.f, 0.f};
  f32x4 acc[2][8];
  f32x4 lacc[2];
#pragma unroll
  for (int m = 0; m < 2; ++m) {
    lacc[m] = z;
#pragma unroll
    for (int cc = 0; cc < 8; ++cc) acc[m][cc] = z;
  }
  const _Float16 one = (_Float16)1.0f;
  const f16x8 ones = {one, one, one, one, one, one, one, one};

  f16x8 ka[8], va[8], kb[8], vb[8];

  LDK(ka, 0);
  LDV(va, 0);
  for (int it = 0; it < 64; it += 2) {
    LDK(kb, it + 1);
    LDV(vb, it + 1);
    COMPUTE(ka, va);
    const int nx = (it + 2) & 63;  // wraps to 0 on final pair: harmless warm reload
    LDK(ka, nx);
    LDV(va, nx);
    COMPUTE(kb, vb);
    if ((it & 14) == 14) __syncthreads();  // convoy barrier: keep waves L1-coherent
  }

  // ---- epilogue: combine mixes in-register, LDS transpose, coalesced store ----
  const float w0 = prior[b * 2 + 0], w1 = prior[b * 2 + 1];
  const float r0 = w0 / lacc[0][0];
  const float r1 = w1 / lacc[1][0];
  __shared__ float obuf[4][16][132];
#pragma unroll
  for (int cc = 0; cc < 8; ++cc) {
    f32x4 o;
#pragma unroll
    for (int e = 0; e < 4; ++e) o[e] = acc[0][cc][e] * r0 + acc[1][cc][e] * r1;
    *(f32x4*)&obuf[wv][l16][cc * 16 + quad * 4] = o;
  }
  __syncthreads();
  const int row = threadIdx.x >> 2;        // 0..63
  const int w = row >> 4, ql = row & 15;
  const int cb = (threadIdx.x & 3) * 4;
  float* op = out + ((size_t)b * NN + qb * 64 + row) * DK;
#pragma unroll
  for (int g = 0; g < 8; ++g)
    *(f32x4*)(op + cb + g * 16) = *(const f32x4*)&obuf[w][ql][cb + g * 16];
}

extern "C" void kernel_launch(void* const* d_in, const int* in_sizes, int n_in,
                              void* d_out, int out_size, void* d_ws, size_t ws_size,
                              hipStream_t stream) {
  const float* qt = (const float*)d_in[0];
  const float* kt = (const float*)d_in[1];
  const float* vt = (const float*)d_in[2];
  const float* kern = (const float*)d_in[3];
  float* out = (float*)d_out;

  char* ws = (char*)d_ws;
  float* prior = (float*)ws;                 // 16 floats
  float* partial = (float*)ws + 256;         // 64*128 floats (32 KB)
  _Float16* khp = (_Float16*)(ws + 65536);   // 2M halfs (4 MB)
  _Float16* vTp = khp + (size_t)BS * NN * DK;

  prep_k<<<dim3(4160), dim3(256), 0, stream>>>(kt, khp, vt, vTp, qt, partial);
  prior_k<<<dim3(1), dim3(256), 0, stream>>>(kern, partial, prior);
  attn_k<<<dim3(256), dim3(256), 0, stream>>>(qt, khp, vTp, prior, out);
}

// Round 6
// 126.171 us; speedup vs baseline: 6.7547x; 1.6145x over previous
//
#include <hip/hip_runtime.h>
#include <hip/hip_fp16.h>

typedef float    f32x4 __attribute__((ext_vector_type(4)));
typedef _Float16 f16x2 __attribute__((ext_vector_type(2)));
typedef _Float16 f16x4 __attribute__((ext_vector_type(4)));
typedef _Float16 f16x8 __attribute__((ext_vector_type(8)));

#define BS 8
#define NN 2048
#define DK 128
#define DM 64
#define MIXOFF (1024 * DK)  // halfs between mix-0 and mix-1 rows of one batch
// log2(e) / sqrt(128): folds softmax temperature AND exp->exp2 conversion into Q
#define QSCALE 0.12751744116926208f

#define MFMA32(a, b, c) __builtin_amdgcn_mfma_f32_16x16x32_f16((a), (b), (c), 0, 0, 0)
#define EXP2(x) __builtin_amdgcn_exp2f(x)

__device__ __forceinline__ f16x2 pkrtz(float x, float y) {
  return __builtin_bit_cast(f16x2, __builtin_amdgcn_cvt_pkrtz(x, y));
}

// async global->LDS DMA, 16B per lane; no VGPR transit (allocator-proof)
__device__ __forceinline__ void load_lds16(const _Float16* g, _Float16* l) {
  __builtin_amdgcn_global_load_lds(
      (const __attribute__((address_space(1))) void*)(uintptr_t)g,
      (__attribute__((address_space(3))) void*)(uint32_t)(uintptr_t)l, 16, 0, 0);
}

// ---- fused prep: K f32->f16 (512 blk), V transpose 64x64 (512 blk), q-mean (64 blk) ----
__global__ void prep_k(const float* __restrict__ kt, _Float16* __restrict__ kh,
                       const float* __restrict__ vt, _Float16* __restrict__ vT,
                       const float* __restrict__ qt, float* __restrict__ partial) {
  __shared__ float tile[64][65];
  __shared__ float red[256];
  int blk = blockIdx.x;
  int t = threadIdx.x;
  if (blk < 512) {
    size_t base = (size_t)blk * 4096;
#pragma unroll
    for (int j = 0; j < 4; ++j) {
      size_t i = base + j * 1024 + t * 4;
      f32x4 v = *(const f32x4*)(kt + i);
      f16x4 h;
      h[0] = (_Float16)v[0]; h[1] = (_Float16)v[1];
      h[2] = (_Float16)v[2]; h[3] = (_Float16)v[3];
      *(f16x4*)(kh + i) = h;
    }
  } else if (blk < 1024) {
    int i2 = blk - 512;
    int b = i2 >> 6;
    int rem = i2 & 63;
    int j0 = (rem & 31) * 64;   // key tile
    int c0 = (rem >> 5) * 64;   // channel tile
    int tx = t & 63, ty = t >> 6;
    const float* src = vt + ((size_t)b * NN + j0) * DK + c0;
#pragma unroll
    for (int rr = 0; rr < 16; ++rr) {
      int row = ty * 16 + rr;
      tile[row][tx] = src[(size_t)row * DK + tx];
    }
    __syncthreads();
    _Float16* dst = vT + ((size_t)b * DK + c0) * NN + j0;
    int chl = t >> 4;
    int k4 = (t & 15) * 4;
#pragma unroll
    for (int r2 = 0; r2 < 4; ++r2) {
      int ch = r2 * 16 + chl;
      f16x4 h;
      h[0] = (_Float16)tile[k4 + 0][ch]; h[1] = (_Float16)tile[k4 + 1][ch];
      h[2] = (_Float16)tile[k4 + 2][ch]; h[3] = (_Float16)tile[k4 + 3][ch];
      *(f16x4*)(dst + (size_t)ch * NN + k4) = h;
    }
  } else {
    int i = blk - 1024;
    int b = i >> 3, seg = i & 7;
    int c = t & 127, h = t >> 7;
    const float* p = qt + ((size_t)b * NN + seg * 256 + h * 128) * DK + c;
    float s = 0.f;
#pragma unroll 8
    for (int n = 0; n < 128; ++n) s += p[(size_t)n * DK];
    red[t] = s;
    __syncthreads();
    if (t < 128) partial[(size_t)i * 128 + t] = red[t] + red[t + 128];
  }
}

// Stage one 32-key iteration tile (16KB) into LDS buffer BUF via global_load_lds.
// Unit map: 0..255 K mix0 (row r, 8x16B units XOR-swizzled by g(r)=(r&3)^2(r>>3)),
// 256..511 K mix1, 512..1023 V (channel ch, 4 units XOR by h2(ch)=(ch+(ch>>2))&3).
#define STAGE(BUF, IT) do {                                                     \
    _Float16* dst0_ = stg + (BUF) * 8192;                                       \
    _Pragma("unroll")                                                           \
    for (int j_ = 0; j_ < 4; ++j_) {                                            \
      int unit_ = j_ * 256 + (int)threadIdx.x;                                  \
      const _Float16* g_;                                                       \
      if (unit_ < 512) {                                                        \
        int mix_ = unit_ >> 8, qq_ = unit_ & 255, r_ = qq_ >> 3;                \
        int uu_ = (qq_ & 7) ^ ((r_ & 3) ^ ((r_ >> 3) << 1));                    \
        g_ = kh + bq + mix_ * MIXOFF + (size_t)((IT) * 32 + r_) * 64 + uu_ * 8; \
      } else {                                                                  \
        int qq_ = unit_ - 512, ch_ = qq_ >> 2;                                  \
        int uu_ = (qq_ & 3) ^ ((ch_ + (ch_ >> 2)) & 3);                         \
        g_ = vT + bV + (size_t)ch_ * NN + (IT) * 32 + uu_ * 8;                  \
      }                                                                         \
      load_lds16(g_, dst0_ + unit_ * 8);                                        \
    }                                                                           \
  } while (0)

#define ITER(BUF, IT) do {                                                      \
    __syncthreads(); /* buf BUF ready (vmcnt drain); prev reads of BUF^1 done */\
    if ((IT) + 1 < 64) STAGE((BUF) ^ 1, (IT) + 1);                              \
    const _Float16* sb_ = stg + (BUF) * 8192;                                   \
    f16x8 kf[8], vf[8];                                                         \
    kf[0] = *(const f16x8*)(sb_ + kr0 + kA);                                    \
    kf[1] = *(const f16x8*)(sb_ + kr0 + kB);                                    \
    kf[2] = *(const f16x8*)(sb_ + 2048 + kr0 + kA);                             \
    kf[3] = *(const f16x8*)(sb_ + 2048 + kr0 + kB);                             \
    kf[4] = *(const f16x8*)(sb_ + kr1 + kA);                                    \
    kf[5] = *(const f16x8*)(sb_ + kr1 + kB);                                    \
    kf[6] = *(const f16x8*)(sb_ + 2048 + kr1 + kA);                             \
    kf[7] = *(const f16x8*)(sb_ + 2048 + kr1 + kB);                             \
    _Pragma("unroll")                                                           \
    for (int cc = 0; cc < 8; ++cc)                                              \
      vf[cc] = *(const f16x8*)(sb_ + vbase + cc * 512);                         \
    f32x4 s[2][2];                                                              \
    s[0][0] = MFMA32(kf[1], qf[0][1], MFMA32(kf[0], qf[0][0], z));              \
    s[1][0] = MFMA32(kf[3], qf[1][1], MFMA32(kf[2], qf[1][0], z));              \
    s[0][1] = MFMA32(kf[5], qf[0][1], MFMA32(kf[4], qf[0][0], z));              \
    s[1][1] = MFMA32(kf[7], qf[1][1], MFMA32(kf[6], qf[1][0], z));              \
    _Pragma("unroll")                                                           \
    for (int m = 0; m < 2; ++m) {                                               \
      union { f16x8 v; f16x2 h[4]; } w_;                                        \
      w_.h[0] = pkrtz(EXP2(s[m][0][0]), EXP2(s[m][0][1]));                      \
      w_.h[1] = pkrtz(EXP2(s[m][0][2]), EXP2(s[m][0][3]));                      \
      w_.h[2] = pkrtz(EXP2(s[m][1][0]), EXP2(s[m][1][1]));                      \
      w_.h[3] = pkrtz(EXP2(s[m][1][2]), EXP2(s[m][1][3]));                      \
      lacc[m] = MFMA32(ones, w_.v, lacc[m]);                                    \
      _Pragma("unroll")                                                         \
      for (int cc = 0; cc < 8; ++cc)                                            \
        acc[m][cc] = MFMA32(vf[cc], w_.v, acc[m][cc]);                          \
    }                                                                           \
  } while (0)

// ---------------- main: mixture flash attention, LDS-staged m97 structure -------
// grid 256 (1 blk/CU): b = blk&7, qb = blk>>3. 4 waves split queries (16 q each),
// SHARE the LDS K/V tile (VMEM/CU traffic /4). Double-buffered LDS staging via
// global_load_lds (no VGPR transit -> allocator can't serialize it, cf. R5).
// Pipeline: barrier -> stage(next) -> ds_read+compute(cur): prefetch flies under
// the compute window; barrier's vmcnt(0) drain finds it landed. XOR swizzles make
// every ds_read_b128 2-way-per-bank (free). Prior softmax computed redundantly
// per block in the epilogue (kills a kernel launch).
__global__ __launch_bounds__(256) void attn_k(const float* __restrict__ qt,
                                              const _Float16* __restrict__ kh,
                                              const _Float16* __restrict__ vT,
                                              const float* __restrict__ kern,
                                              const float* __restrict__ partial,
                                              float* __restrict__ out) {
  __shared__ __align__(16) char smem[40960];
  _Float16* stg = (_Float16*)smem;  // [2][8192] halfs = 2 x 16KB
  const int b = blockIdx.x & 7;
  const int qb = blockIdx.x >> 3;
  const int wv = threadIdx.x >> 6;
  const int lane = threadIdx.x & 63;
  const int quad = lane >> 4, l16 = lane & 15;
  const int perm = ((l16 >> 2) << 3) | (l16 & 3);
  const size_t bq = (size_t)b * (NN * DK);
  const size_t bV = (size_t)b * (DK * NN);
  const int q0 = qb * 64 + wv * 16;

  // Q fragments: f32 load + scale + pack to f16 in-register
  f16x8 qf[2][2];  // [mix][chunk]
#pragma unroll
  for (int m = 0; m < 2; ++m)
#pragma unroll
    for (int c = 0; c < 2; ++c) {
      const float* qp = qt + bq + (size_t)m * (1024 * DK) +
                        (size_t)(q0 + l16) * DM + quad * 8 + c * 32;
      f32x4 v0 = *(const f32x4*)qp;
      f32x4 v1 = *(const f32x4*)(qp + 4);
      union { f16x8 v; f16x2 h[4]; } w;
      w.h[0] = pkrtz(v0[0] * QSCALE, v0[1] * QSCALE);
      w.h[1] = pkrtz(v0[2] * QSCALE, v0[3] * QSCALE);
      w.h[2] = pkrtz(v1[0] * QSCALE, v1[1] * QSCALE);
      w.h[3] = pkrtz(v1[2] * QSCALE, v1[3] * QSCALE);
      qf[m][c] = w.v;
    }

  // LDS read offsets (halfs), swizzles matching STAGE's unit map
  const int gK = (l16 & 3) ^ ((l16 >> 2) << 1);
  const int hV = (l16 + (l16 >> 2)) & 3;
  const int kA = (quad ^ gK) * 8;        // chunk 0 unit
  const int kB = ((quad + 4) ^ gK) * 8;  // chunk 1 unit
  const int kr0 = perm * 64;             // subtile-0 row
  const int kr1 = (perm + 4) * 64;       // subtile-1 row
  const int vbase = 4096 + l16 * 32 + (quad ^ hV) * 8;

  const f32x4 z = {0.f, 0.f, 0.f, 0.f};
  f32x4 acc[2][8];
  f32x4 lacc[2];
#pragma unroll
  for (int m = 0; m < 2; ++m) {
    lacc[m] = z;
#pragma unroll
    for (int cc = 0; cc < 8; ++cc) acc[m][cc] = z;
  }
  const _Float16 one = (_Float16)1.0f;
  const f16x8 ones = {one, one, one, one, one, one, one, one};

  STAGE(0, 0);
  for (int it = 0; it < 64; it += 2) {
    ITER(0, it);
    ITER(1, it + 1);
  }

  // ---- epilogue: prior softmax (redundant per block), combine, store ----
  __syncthreads();  // all LDS tile reads done; overlay region reuse below
  float* obuf = (float*)smem;                          // [4][16][132] floats
  float* barL = (float*)(smem + 33792);                // [8][128]
  float* lgp = (float*)(smem + 33792 + 4096);          // [16]
  float* exq = lgp + 16;                               // [16]
  float* prp = lgp + 32;                               // [16]

  for (int e = threadIdx.x; e < 1024; e += 256) {
    int bb = e >> 7, c = e & 127;
    float s = 0.f;
#pragma unroll
    for (int seg = 0; seg < 8; ++seg) s += partial[(size_t)(bb * 8 + seg) * 128 + c];
    barL[bb * 128 + c] = s * (1.0f / 2048.0f);
  }
  __syncthreads();
  if (threadIdx.x < 16) {
    int m = threadIdx.x >> 3, bb = threadIdx.x & 7;
    float s = 0.f;
    for (int c = 0; c < DK; ++c) s += kern[m * DK + c] * barL[bb * 128 + c];
    lgp[threadIdx.x] = s;
  }
  __syncthreads();
  if (threadIdx.x < 16) {
    int m = threadIdx.x >> 3;
    float mx = lgp[m * 8];
    for (int i = 1; i < 8; ++i) mx = fmaxf(mx, lgp[m * 8 + i]);
    exq[threadIdx.x] = __expf(lgp[threadIdx.x] - mx);
  }
  __syncthreads();
  if (threadIdx.x < 16) {
    int m = threadIdx.x >> 3;
    float sm = 0.f;
    for (int i = 0; i < 8; ++i) sm += exq[m * 8 + i];
    prp[threadIdx.x] = exq[threadIdx.x] / sm;  // flat[m*8+b]; read as [b*2+m] (TF quirk)
  }
  __syncthreads();
  const float w0 = prp[b * 2 + 0], w1 = prp[b * 2 + 1];
  const float r0 = w0 / lacc[0][0];
  const float r1 = w1 / lacc[1][0];
#pragma unroll
  for (int cc = 0; cc < 8; ++cc) {
    f32x4 o;
#pragma unroll
    for (int e = 0; e < 4; ++e) o[e] = acc[0][cc][e] * r0 + acc[1][cc][e] * r1;
    *(f32x4*)&obuf[(wv * 16 + l16) * 132 + cc * 16 + quad * 4] = o;
  }
  __syncthreads();
  const int row = threadIdx.x >> 2;
  const int w = row >> 4, ql = row & 15;
  const int cb = (threadIdx.x & 3) * 4;
  float* op = out + ((size_t)b * NN + qb * 64 + row) * DK;
#pragma unroll
  for (int g2 = 0; g2 < 8; ++g2)
    *(f32x4*)(op + cb + g2 * 16) = *(const f32x4*)&obuf[(w * 16 + ql) * 132 + cb + g2 * 16];
}

extern "C" void kernel_launch(void* const* d_in, const int* in_sizes, int n_in,
                              void* d_out, int out_size, void* d_ws, size_t ws_size,
                              hipStream_t stream) {
  const float* qt = (const float*)d_in[0];
  const float* kt = (const float*)d_in[1];
  const float* vt = (const float*)d_in[2];
  const float* kern = (const float*)d_in[3];
  float* out = (float*)d_out;

  char* ws = (char*)d_ws;
  float* partial = (float*)ws;               // 64*128 floats (32 KB)
  _Float16* khp = (_Float16*)(ws + 65536);   // 2M halfs (4 MB)
  _Float16* vTp = khp + (size_t)BS * NN * DK;

  prep_k<<<dim3(1088), dim3(256), 0, stream>>>(kt, khp, vt, vTp, qt, partial);
  attn_k<<<dim3(256), dim3(256), 0, stream>>>(qt, khp, vTp, kern, partial, out);
}